// Round 18
// baseline (254.303 us; speedup 1.0000x reference)
//
#include <hip/hip_runtime.h>
#include <math.h>

#define HID 256
#define INDIM 128
#define NXCD 8
#define NSLICE 128   // edge slices per dst-range; fill grid = NXCD*NSLICE

typedef short s16x8 __attribute__((ext_vector_type(8)));
typedef float f32x4 __attribute__((ext_vector_type(4)));
typedef float f32x2 __attribute__((ext_vector_type(2)));

// ---- bf16 helpers (RNE, finite inputs) ----
static __device__ __forceinline__ unsigned short f2bf(float f) {
    unsigned int u = __float_as_uint(f);
    unsigned int r = (u + 0x7fffu + ((u >> 16) & 1u)) >> 16;
    return (unsigned short)r;
}

// ---- fp8 e4m3 decode, packed accumulate (f32x2 += f32x2 -> v_pk_add_f32) ----
#define DECWP(a, base, w)                                                  \
    do {                                                                   \
        a[(base) + 0] += __builtin_amdgcn_cvt_pk_f32_fp8((int)(w), false); \
        a[(base) + 1] += __builtin_amdgcn_cvt_pk_f32_fp8((int)(w), true);  \
    } while (0)
#define DEC16P(a, u)                                                       \
    do { DECWP(a, 0, (u).x); DECWP(a, 2, (u).y);                           \
         DECWP(a, 4, (u).z); DECWP(a, 6, (u).w); } while (0)

// ---------------- in-degree count: int4-batched single pass ----------------
__global__ void k_count(const int* __restrict__ dst, int E, int* cnt) {
    int n4 = E >> 2;
    int i = blockIdx.x * blockDim.x + threadIdx.x;
    if (i < n4) {
        int4 d = ((const int4*)dst)[i];
        atomicAdd(&cnt[d.x], 1);
        atomicAdd(&cnt[d.y], 1);
        atomicAdd(&cnt[d.z], 1);
        atomicAdd(&cnt[d.w], 1);
    }
    if (i == 0) {
        for (int e = n4 << 2; e < E; e++) atomicAdd(&cnt[dst[e]], 1);
    }
}

// ---------------- 2-level exclusive scan ----------------
__global__ __launch_bounds__(256) void k_scan_block(const int* __restrict__ cnt,
                                                    int* excl_tmp, int* blksum, int n) {
    __shared__ int sm[256];
    int t = threadIdx.x;
    int i = blockIdx.x * 256 + t;
    int c = (i < n) ? cnt[i] : 0;
    sm[t] = c;
    __syncthreads();
    for (int off = 1; off < 256; off <<= 1) {
        int v = (t >= off) ? sm[t - off] : 0;
        __syncthreads();
        sm[t] += v;
        __syncthreads();
    }
    if (i < n) excl_tmp[i] = sm[t] - c;
    if (t == 255) blksum[blockIdx.x] = sm[255];
}

__global__ __launch_bounds__(256) void k_scan_top(int* blksum, int nb) {
    __shared__ int sm[256];
    int t = threadIdx.x;
    int c = (t < nb) ? blksum[t] : 0;
    sm[t] = c;
    __syncthreads();
    for (int off = 1; off < 256; off <<= 1) {
        int v = (t >= off) ? sm[t - off] : 0;
        __syncthreads();
        sm[t] += v;
        __syncthreads();
    }
    if (t < nb) blksum[t] = sm[t] - c;
}

// rows + cursor + dinv in one pass
__global__ __launch_bounds__(256) void k_finalize_rows(const int* __restrict__ excl_tmp,
                                                       const int* __restrict__ blksum,
                                                       const int* __restrict__ cnt,
                                                       int* row_start, int* cursor,
                                                       float* dinv, int n, int E) {
    int i = blockIdx.x * 256 + threadIdx.x;
    if (i < n) {
        int r = excl_tmp[i] + blksum[blockIdx.x];
        row_start[i] = r;
        cursor[i] = r;
        dinv[i] = rsqrtf((float)(cnt[i] + 1));
    }
    if (i == 0) row_start[n] = E;
}

// ---- CSR fill: XCD-range partitioned + int4-batched edge scan.
// Block handles dst-range r = blockIdx%8 (one XCD per range under round-robin
// dispatch -> csr window lines merge in that XCD's L2) and int4 edge-slice
// s = blockIdx/8. 4 edges per thread-iteration, independent loads.
__global__ void k_fill(const int* __restrict__ src, const int* __restrict__ dst,
                       int E, int* cursor, int* __restrict__ csr_src, int n) {
    int r = blockIdx.x & (NXCD - 1);
    int s = blockIdx.x / NXCD;
    int range = (n + NXCD - 1) / NXCD;
    int lo = r * range, hi = lo + range;
    int n4 = E >> 2;
    int per = (n4 + NSLICE - 1) / NSLICE;
    int c0 = s * per;
    int c1 = c0 + per; if (c1 > n4) c1 = n4;
    for (int c = c0 + threadIdx.x; c < c1; c += blockDim.x) {
        int4 d = ((const int4*)dst)[c];
        int e = c << 2;
        if (d.x >= lo && d.x < hi) { int p = atomicAdd(&cursor[d.x], 1); csr_src[p] = src[e]; }
        if (d.y >= lo && d.y < hi) { int p = atomicAdd(&cursor[d.y], 1); csr_src[p] = src[e + 1]; }
        if (d.z >= lo && d.z < hi) { int p = atomicAdd(&cursor[d.z], 1); csr_src[p] = src[e + 2]; }
        if (d.w >= lo && d.w < hi) { int p = atomicAdd(&cursor[d.w], 1); csr_src[p] = src[e + 3]; }
    }
    // tail edges (E not multiple of 4): handled once by block 0
    if (blockIdx.x == 0 && threadIdx.x == 0) {
        for (int e = n4 << 2; e < E; e++) {
            int d = dst[e];
            int p = atomicAdd(&cursor[d], 1);
            csr_src[p] = src[e];
        }
    }
}

// ---------------- cast + dinv scale to fp8: xq = fp8(x * dinv[row]) -------
__global__ void k_cast_q(const float* __restrict__ x, const float* __restrict__ dinv,
                         unsigned int* __restrict__ out, int nw) {
    int i = blockIdx.x * blockDim.x + threadIdx.x;  // word idx; INDIM/4=32 per row
    if (i < nw) {
        float dv = dinv[i >> 5];
        float4 v = ((const float4*)x)[i];
        int w0 = __builtin_amdgcn_cvt_pk_fp8_f32(v.x * dv, v.y * dv, 0, false);
        w0 = __builtin_amdgcn_cvt_pk_fp8_f32(v.z * dv, v.w * dv, w0, true);
        out[i] = (unsigned int)w0;
    }
}

// ---- weight -> fragment-linear bf16 layout ----
template <int K>
__global__ void k_wtf(const float* __restrict__ W, uint4* __restrict__ Wfrag) {
    constexpr int NK = K / 32;
    int c_tile = blockIdx.x / NK;
    int kk = blockIdx.x % NK;
    int lane = threadIdx.x;
    int c = c_tile * 16 + (lane & 15);
    int k0 = kk * 32 + (lane >> 4) * 8;
    unsigned short b[8];
#pragma unroll
    for (int j = 0; j < 8; j++) b[j] = f2bf(W[(size_t)(k0 + j) * HID + c]);
    uint4 o;
    o.x = (unsigned int)b[0] | ((unsigned int)b[1] << 16);
    o.y = (unsigned int)b[2] | ((unsigned int)b[3] << 16);
    o.z = (unsigned int)b[4] | ((unsigned int)b[5] << 16);
    o.w = (unsigned int)b[6] | ((unsigned int)b[7] << 16);
    Wfrag[(size_t)(c_tile * NK + kk) * 64 + lane] = o;
}

// ---- MFMA GEMM, B staged in LDS (fragment-linear, conflict-free) ----
template <int K, int EPI>
__global__ __launch_bounds__(256) void k_gemm_mfma(const unsigned short* __restrict__ Xb,
                                                   const uint4* __restrict__ Wfrag,
                                                   const float* __restrict__ epi,
                                                   void* __restrict__ Yout, int n) {
    constexpr int NK = K / 32;
    __shared__ uint4 bl[4 * NK * 64];

    const int nb = blockIdx.x & 3;          // col quarter
    const int mb = blockIdx.x >> 2;         // row block
    const int r0 = mb * 128;
    const int w = threadIdx.x >> 6;
    const int lane = threadIdx.x & 63;
    const int ar = lane & 15;
    const int ak = (lane >> 4) * 8;

    {
        const uint4* gsrc = Wfrag + (size_t)nb * 4 * NK * 64;
        for (int i = threadIdx.x; i < 4 * NK * 64; i += 256) bl[i] = gsrc[i];
    }

    int arow[2];
#pragma unroll
    for (int rt = 0; rt < 2; rt++) {
        int r = r0 + w * 32 + rt * 16 + ar;
        arow[rt] = (r < n) ? r : n - 1;  // clamp (store guarded)
    }

    f32x4 acc[2][4];
#pragma unroll
    for (int rt = 0; rt < 2; rt++)
#pragma unroll
        for (int ct = 0; ct < 4; ct++) acc[rt][ct] = f32x4{0, 0, 0, 0};

    __syncthreads();

    s16x8 a_cur[2], a_nxt[2];
#pragma unroll
    for (int rt = 0; rt < 2; rt++)
        a_cur[rt] = *(const s16x8*)(Xb + (size_t)arow[rt] * K + ak);

#pragma unroll
    for (int kk = 0; kk < NK; kk++) {
        if (kk + 1 < NK) {
#pragma unroll
            for (int rt = 0; rt < 2; rt++)
                a_nxt[rt] = *(const s16x8*)(Xb + (size_t)arow[rt] * K + (kk + 1) * 32 + ak);
        }
        s16x8 bfrag[4];
#pragma unroll
        for (int ct = 0; ct < 4; ct++)
            bfrag[ct] = ((const s16x8*)bl)[(ct * NK + kk) * 64 + lane];
#pragma unroll
        for (int rt = 0; rt < 2; rt++)
#pragma unroll
            for (int ct = 0; ct < 4; ct++)
                acc[rt][ct] = __builtin_amdgcn_mfma_f32_16x16x32_bf16(a_cur[rt], bfrag[ct],
                                                                      acc[rt][ct], 0, 0, 0);
#pragma unroll
        for (int rt = 0; rt < 2; rt++) a_cur[rt] = a_nxt[rt];
    }

#pragma unroll
    for (int rt = 0; rt < 2; rt++) {
        int rbase = r0 + w * 32 + rt * 16 + (lane >> 4) * 4;
        if constexpr (EPI == 1) {
            unsigned short* Yb = (unsigned short*)Yout;
#pragma unroll
            for (int ct = 0; ct < 4; ct++) {
                int c = nb * 64 + ct * 16 + ar;
                float bc = epi[c];
#pragma unroll
                for (int j = 0; j < 4; j++) {
                    int r = rbase + j;
                    if (r < n) Yb[(size_t)r * HID + c] = f2bf(fmaxf(acc[rt][ct][j] + bc, 0.0f));
                }
            }
        } else {
            unsigned char* Yq = (unsigned char*)Yout;
            float dv[4];
#pragma unroll
            for (int j = 0; j < 4; j++) dv[j] = (rbase + j < n) ? epi[rbase + j] : 0.0f;
#pragma unroll
            for (int ct = 0; ct < 4; ct++) {
                int c = nb * 64 + ct * 16 + ar;
#pragma unroll
                for (int j = 0; j < 4; j++) {
                    int r = rbase + j;
                    if (r < n) {
                        float f = acc[rt][ct][j] * dv[j];
                        int e = __builtin_amdgcn_cvt_pk_fp8_f32(f, f, 0, false);
                        Yq[(size_t)r * HID + c] = (unsigned char)(e & 0xff);
                    }
                }
            }
        }
    }
}

// ---- gather-aggregate fp8 -> bf16, zero-row padded (index n = zeros) ----
template <int D, bool BIASRELU>
__global__ __launch_bounds__(256) void k_agg_q(const unsigned char* __restrict__ Hq,
                                               const float* __restrict__ dinv,
                                               const int* __restrict__ row_start,
                                               const int* __restrict__ csr_src,
                                               const float* __restrict__ bias,
                                               unsigned short* __restrict__ O, int n) {
    constexpr int LPR = D / 16;
    constexpr int EPW = 64 / LPR;
    const int v = blockIdx.x * 4 + (threadIdx.x >> 6);
    const int lane = threadIdx.x & 63;
    const int sub = lane / LPR;
    const int li = lane % LPR;
    if (v >= n) return;
    const uint4* H4 = (const uint4*)Hq;
    f32x2 a[8];
#pragma unroll
    for (int k = 0; k < 8; k++) a[k] = f32x2{0.f, 0.f};
    const int beg = row_start[v], end = row_start[v + 1];
    const int last = end - 1;
    for (int i = beg + sub; i < end; i += 4 * EPW) {
        int j1 = i + EPW, j2 = i + 2 * EPW, j3 = i + 3 * EPW;
        int s0 = csr_src[i];
        int t1 = csr_src[j1 <= last ? j1 : last];
        int t2 = csr_src[j2 <= last ? j2 : last];
        int t3 = csr_src[j3 <= last ? j3 : last];
        int s1 = (j1 < end) ? t1 : n;   // n == zero row
        int s2 = (j2 < end) ? t2 : n;
        int s3 = (j3 < end) ? t3 : n;
        uint4 u0 = H4[(size_t)s0 * LPR + li];
        uint4 u1 = H4[(size_t)s1 * LPR + li];
        uint4 u2 = H4[(size_t)s2 * LPR + li];
        uint4 u3 = H4[(size_t)s3 * LPR + li];
        DEC16P(a, u0); DEC16P(a, u1); DEC16P(a, u2); DEC16P(a, u3);
    }
    // combine partial sums across edge-slots (butterfly)
#pragma unroll
    for (int off = LPR; off < 64; off <<= 1)
#pragma unroll
        for (int k = 0; k < 8; k++) {
            a[k][0] += __shfl_xor(a[k][0], off);
            a[k][1] += __shfl_xor(a[k][1], off);
        }

    if (lane < LPR) {
        uint4 us = H4[(size_t)v * LPR + li];  // self term
        DEC16P(a, us);
        float dv = dinv[v];
        float o[16];
        if constexpr (BIASRELU) {
            const float4* B4 = (const float4*)bias;
#pragma unroll
            for (int q = 0; q < 4; q++) {
                float4 bb = B4[li * 4 + q];
                o[q * 4 + 0] = fmaxf(fmaf(dv, a[q * 2 + 0][0], bb.x), 0.f);
                o[q * 4 + 1] = fmaxf(fmaf(dv, a[q * 2 + 0][1], bb.y), 0.f);
                o[q * 4 + 2] = fmaxf(fmaf(dv, a[q * 2 + 1][0], bb.z), 0.f);
                o[q * 4 + 3] = fmaxf(fmaf(dv, a[q * 2 + 1][1], bb.w), 0.f);
            }
        } else {
#pragma unroll
            for (int k = 0; k < 8; k++) {
                o[k * 2 + 0] = dv * a[k][0];
                o[k * 2 + 1] = dv * a[k][1];
            }
        }
        uint4 ow0, ow1;
        ow0.x = (unsigned int)f2bf(o[0]) | ((unsigned int)f2bf(o[1]) << 16);
        ow0.y = (unsigned int)f2bf(o[2]) | ((unsigned int)f2bf(o[3]) << 16);
        ow0.z = (unsigned int)f2bf(o[4]) | ((unsigned int)f2bf(o[5]) << 16);
        ow0.w = (unsigned int)f2bf(o[6]) | ((unsigned int)f2bf(o[7]) << 16);
        ow1.x = (unsigned int)f2bf(o[8]) | ((unsigned int)f2bf(o[9]) << 16);
        ow1.y = (unsigned int)f2bf(o[10]) | ((unsigned int)f2bf(o[11]) << 16);
        ow1.z = (unsigned int)f2bf(o[12]) | ((unsigned int)f2bf(o[13]) << 16);
        ow1.w = (unsigned int)f2bf(o[14]) | ((unsigned int)f2bf(o[15]) << 16);
        uint4* Op = (uint4*)O + (size_t)v * (2 * LPR) + li * 2;
        Op[0] = ow0;
        Op[1] = ow1;
    }
}

#define BFLO(x) __uint_as_float((x) << 16)
#define BFHI(x) __uint_as_float((x) & 0xffff0000u)
#define ACC8(a, u)                                  \
    do {                                            \
        a[0] += BFLO((u).x); a[1] += BFHI((u).x);   \
        a[2] += BFLO((u).y); a[3] += BFHI((u).y);   \
        a[4] += BFLO((u).z); a[5] += BFHI((u).z);   \
        a[6] += BFLO((u).w); a[7] += BFHI((u).w);   \
    } while (0)

// ---------------- mean pool per graph (bf16 in, fp32 out) ----------------
__global__ __launch_bounds__(256) void k_pool(const unsigned short* __restrict__ Hb,
                                              const int* __restrict__ batch,
                                              int n, float* __restrict__ G) {
    int g = blockIdx.x;
    int w = threadIdx.x >> 6;
    int lane = threadIdx.x & 63;
    int sub = lane >> 5;
    int li = lane & 31;
    int lo = 0, hi = n;
    while (lo < hi) { int m = (lo + hi) >> 1; if (batch[m] < g) lo = m + 1; else hi = m; }
    int start = lo;
    hi = n;
    while (lo < hi) { int m = (lo + hi) >> 1; if (batch[m] <= g) lo = m + 1; else hi = m; }
    int end = lo;
    const uint4* H4 = (const uint4*)Hb;
    float a[8] = {0, 0, 0, 0, 0, 0, 0, 0};
    for (int v = start + w * 2 + sub; v < end; v += 8) {
        uint4 u = H4[(size_t)v * 32 + li];
        ACC8(a, u);
    }
#pragma unroll
    for (int k = 0; k < 8; k++) a[k] += __shfl_xor(a[k], 32);
    __shared__ float red[4][32][8];
    if (lane < 32) {
#pragma unroll
        for (int k = 0; k < 8; k++) red[w][li][k] = a[k];
    }
    __syncthreads();
    if (w == 0 && lane < 32) {
        float inv = 1.0f / fmaxf((float)(end - start), 1.0f);
        float o[8];
#pragma unroll
        for (int k = 0; k < 8; k++)
            o[k] = (red[0][li][k] + red[1][li][k] + red[2][li][k] + red[3][li][k]) * inv;
        float4* Gp = (float4*)(G + (size_t)g * HID + li * 8);
        Gp[0] = make_float4(o[0], o[1], o[2], o[3]);
        Gp[1] = make_float4(o[4], o[5], o[6], o[7]);
    }
}

// ---------------- classifier: sigmoid(relu(G@W3+b3)@W4+b4) ----------------
__global__ __launch_bounds__(128) void k_cls(const float* __restrict__ G,
                                             const float* __restrict__ W3,
                                             const float* __restrict__ b3,
                                             const float* __restrict__ W4,
                                             const float* __restrict__ b4,
                                             float* __restrict__ out) {
    __shared__ float gr[256];
    __shared__ float red[2];
    int g = blockIdx.x, t = threadIdx.x;
    gr[t] = G[g * 256 + t];
    gr[t + 128] = G[g * 256 + t + 128];
    __syncthreads();
    float z = b3[t];
    for (int k = 0; k < 256; k++) z += gr[k] * W3[k * 128 + t];
    z = fmaxf(z, 0.0f);
    float p = z * W4[t];
    for (int off = 32; off; off >>= 1) p += __shfl_down(p, off);
    if ((t & 63) == 0) red[t >> 6] = p;
    __syncthreads();
    if (t == 0) {
        float tot = red[0] + red[1] + b4[0];
        out[g] = 1.0f / (1.0f + expf(-tot));
    }
}

// ---------------- launch ----------------
extern "C" void kernel_launch(void* const* d_in, const int* in_sizes, int n_in,
                              void* d_out, int out_size, void* d_ws, size_t ws_size,
                              hipStream_t stream) {
    const float* x  = (const float*)d_in[0];
    const int*   ei = (const int*)d_in[1];
    const int*   batch = (const int*)d_in[2];
    const float* W1 = (const float*)d_in[3];
    const float* b1 = (const float*)d_in[4];
    const float* W2 = (const float*)d_in[5];
    const float* b2 = (const float*)d_in[6];
    const float* W3 = (const float*)d_in[7];
    const float* b3 = (const float*)d_in[8];
    const float* W4 = (const float*)d_in[9];
    const float* b4 = (const float*)d_in[10];

    const int N = in_sizes[2];       // 50000 nodes
    const int E = in_sizes[1] / 2;   // 800000 edges
    const int G = out_size;          // 128 graphs
    const int NB = (N + 255) / 256;

    char* w = (char*)d_ws;
    float* dinv      = (float*)w;  w += ((size_t)N * 4 + 255) & ~(size_t)255;
    int*   cnt       = (int*)w;    w += ((size_t)N * 4 + 255) & ~(size_t)255;
    int*   excl_tmp  = (int*)w;    w += ((size_t)N * 4 + 255) & ~(size_t)255;
    int*   blksum    = (int*)w;    w += 256 * 4;
    int*   row_start = (int*)w;    w += ((size_t)(N + 1) * 4 + 255) & ~(size_t)255;
    int*   cursor    = (int*)w;    w += ((size_t)N * 4 + 255) & ~(size_t)255;
    int*   csr_src   = (int*)w;    w += ((size_t)E * 4 + 255) & ~(size_t)255;
    unsigned char*  xq   = (unsigned char*)w;   w += ((size_t)(N + 1) * INDIM + 255) & ~(size_t)255; // fp8 + zero row
    unsigned char*  Hq   = (unsigned char*)w;   w += ((size_t)(N + 1) * HID + 255) & ~(size_t)255;   // fp8 + zero row
    uint4* wf1 = (uint4*)w;  w += ((size_t)INDIM * HID * 2 + 255) & ~(size_t)255;  // frag-linear bf16
    uint4* wf2 = (uint4*)w;  w += ((size_t)HID * HID * 2 + 255) & ~(size_t)255;    // frag-linear bf16
    unsigned short* bufA = (unsigned short*)w;  w += (size_t)N * INDIM * 2;  // agg1 out (bf16)
    unsigned short* bufB = (unsigned short*)w;  w += (size_t)N * HID * 2;    // h1 / h2 (bf16)
    float* gbuf      = (float*)w;  w += (size_t)G * HID * 4;

    const int* src = ei;
    const int* dst = ei + E;

    // ---- zero rows for clamped gathers ----
    hipMemsetAsync(xq + (size_t)N * INDIM, 0, INDIM, stream);
    hipMemsetAsync(Hq + (size_t)N * HID, 0, HID, stream);

    // ---- weight fragment-linear layout ----
    k_wtf<INDIM><<<16 * (INDIM / 32), 64, 0, stream>>>(W1, wf1);
    k_wtf<HID><<<16 * (HID / 32), 64, 0, stream>>>(W2, wf2);

    // ---- CSR build + dinv ----
    hipMemsetAsync(cnt, 0, (size_t)N * 4, stream);
    k_count<<<(E / 4 + 255) / 256, 256, 0, stream>>>(dst, E, cnt);
    k_scan_block<<<NB, 256, 0, stream>>>(cnt, excl_tmp, blksum, N);
    k_scan_top<<<1, 256, 0, stream>>>(blksum, NB);
    k_finalize_rows<<<NB, 256, 0, stream>>>(excl_tmp, blksum, cnt, row_start, cursor, dinv, N, E);
    k_fill<<<NXCD * NSLICE, 256, 0, stream>>>(src, dst, E, cursor, csr_src, N);

    // ---- scaled fp8 cast: xq = fp8(x * dinv[row]) ----
    int nw = N * INDIM / 4;
    k_cast_q<<<(nw + 255) / 256, 256, 0, stream>>>(x, dinv, (unsigned int*)xq, nw);

    const int gemm_blocks = ((N + 127) / 128) * 4;
    const int agg_blocks  = (N + 3) / 4;

    // ---- layer 1: aggregate (fp8 gather) in 128-dim, then GEMM(+bias+relu) ----
    k_agg_q<INDIM, false><<<agg_blocks, 256, 0, stream>>>(xq, dinv, row_start, csr_src, nullptr, bufA, N);
    k_gemm_mfma<INDIM, 1><<<gemm_blocks, 256, 0, stream>>>(bufA, wf1, b1, bufB, N);

    // ---- layer 2: GEMM(*dinv -> fp8), then aggregate(+bias+relu) in 256-dim ----
    k_gemm_mfma<HID, 2><<<gemm_blocks, 256, 0, stream>>>(bufB, wf2, dinv, Hq, N);
    k_agg_q<HID, true><<<agg_blocks, 256, 0, stream>>>(Hq, dinv, row_start, csr_src, b2, bufB, N);

    // ---- pool + classifier ----
    k_pool<<<G, 256, 0, stream>>>(bufB, batch, N, gbuf);
    k_cls<<<G, 128, 0, stream>>>(gbuf, W3, b3, W4, b4, (float*)d_out);
}

// Round 19
// 245.883 us; speedup vs baseline: 1.0342x; 1.0342x over previous
//
#include <hip/hip_runtime.h>
#include <math.h>

#define HID 256
#define INDIM 128
#define NXCD 8
#define NSLICE 128   // edge slices per dst-range; fill grid = NXCD*NSLICE

typedef short s16x8 __attribute__((ext_vector_type(8)));
typedef float f32x4 __attribute__((ext_vector_type(4)));
typedef float f32x2 __attribute__((ext_vector_type(2)));

// ---- bf16 helpers (RNE, finite inputs) ----
static __device__ __forceinline__ unsigned short f2bf(float f) {
    unsigned int u = __float_as_uint(f);
    unsigned int r = (u + 0x7fffu + ((u >> 16) & 1u)) >> 16;
    return (unsigned short)r;
}

// ---- fp8 e4m3 decode, packed accumulate (f32x2 += f32x2 -> v_pk_add_f32) ----
#define DECWP(a, base, w)                                                  \
    do {                                                                   \
        a[(base) + 0] += __builtin_amdgcn_cvt_pk_f32_fp8((int)(w), false); \
        a[(base) + 1] += __builtin_amdgcn_cvt_pk_f32_fp8((int)(w), true);  \
    } while (0)
#define DEC16P(a, u)                                                       \
    do { DECWP(a, 0, (u).x); DECWP(a, 2, (u).y);                           \
         DECWP(a, 4, (u).z); DECWP(a, 6, (u).w); } while (0)

// ---------------- zero pad rows (single tiny dispatch) ----------------
__global__ void k_zpad(unsigned int* xpad, unsigned int* hpad) {
    int t = threadIdx.x;
    if (t < INDIM / 4) xpad[t] = 0u;
    if (t < HID / 4) hpad[t] = 0u;
}

// ---------------- in-degree count: int4-batched single pass ----------------
__global__ void k_count(const int* __restrict__ dst, int E, int* cnt) {
    int n4 = E >> 2;
    int i = blockIdx.x * blockDim.x + threadIdx.x;
    if (i < n4) {
        int4 d = ((const int4*)dst)[i];
        atomicAdd(&cnt[d.x], 1);
        atomicAdd(&cnt[d.y], 1);
        atomicAdd(&cnt[d.z], 1);
        atomicAdd(&cnt[d.w], 1);
    }
    if (i == 0) {
        for (int e = n4 << 2; e < E; e++) atomicAdd(&cnt[dst[e]], 1);
    }
}

// ---------------- block-level exclusive scan ----------------
__global__ __launch_bounds__(256) void k_scan_block(const int* __restrict__ cnt,
                                                    int* excl_tmp, int* blksum, int n) {
    __shared__ int sm[256];
    int t = threadIdx.x;
    int i = blockIdx.x * 256 + t;
    int c = (i < n) ? cnt[i] : 0;
    sm[t] = c;
    __syncthreads();
    for (int off = 1; off < 256; off <<= 1) {
        int v = (t >= off) ? sm[t - off] : 0;
        __syncthreads();
        sm[t] += v;
        __syncthreads();
    }
    if (i < n) excl_tmp[i] = sm[t] - c;
    if (t == 255) blksum[blockIdx.x] = sm[255];
}

// rows + cursor + dinv; top-level scan of blksum done redundantly per block
// in LDS (nb <= 256), removing the separate scan_top dispatch.
__global__ __launch_bounds__(256) void k_finalize_rows(const int* __restrict__ excl_tmp,
                                                       const int* __restrict__ blksum,
                                                       const int* __restrict__ cnt,
                                                       int* row_start, int* cursor,
                                                       float* dinv, int n, int E, int nb) {
    __shared__ int sm[256];
    __shared__ int orig[256];
    int t = threadIdx.x;
    int c = (t < nb) ? blksum[t] : 0;
    sm[t] = c;
    orig[t] = c;
    __syncthreads();
    for (int off = 1; off < 256; off <<= 1) {
        int v = (t >= off) ? sm[t - off] : 0;
        __syncthreads();
        sm[t] += v;
        __syncthreads();
    }
    int base = sm[blockIdx.x] - orig[blockIdx.x];  // exclusive prefix for this block
    int i = blockIdx.x * 256 + t;
    if (i < n) {
        int r = excl_tmp[i] + base;
        row_start[i] = r;
        cursor[i] = r;
        dinv[i] = rsqrtf((float)(cnt[i] + 1));
    }
    if (i == 0) row_start[n] = E;
}

// ---- CSR fill: XCD-range partitioned + int4-batched edge scan ----
__global__ void k_fill(const int* __restrict__ src, const int* __restrict__ dst,
                       int E, int* cursor, int* __restrict__ csr_src, int n) {
    int r = blockIdx.x & (NXCD - 1);
    int s = blockIdx.x / NXCD;
    int range = (n + NXCD - 1) / NXCD;
    int lo = r * range, hi = lo + range;
    int n4 = E >> 2;
    int per = (n4 + NSLICE - 1) / NSLICE;
    int c0 = s * per;
    int c1 = c0 + per; if (c1 > n4) c1 = n4;
    for (int c = c0 + threadIdx.x; c < c1; c += blockDim.x) {
        int4 d = ((const int4*)dst)[c];
        int e = c << 2;
        if (d.x >= lo && d.x < hi) { int p = atomicAdd(&cursor[d.x], 1); csr_src[p] = src[e]; }
        if (d.y >= lo && d.y < hi) { int p = atomicAdd(&cursor[d.y], 1); csr_src[p] = src[e + 1]; }
        if (d.z >= lo && d.z < hi) { int p = atomicAdd(&cursor[d.z], 1); csr_src[p] = src[e + 2]; }
        if (d.w >= lo && d.w < hi) { int p = atomicAdd(&cursor[d.w], 1); csr_src[p] = src[e + 3]; }
    }
    if (blockIdx.x == 0 && threadIdx.x == 0) {
        for (int e = n4 << 2; e < E; e++) {
            int d = dst[e];
            int p = atomicAdd(&cursor[d], 1);
            csr_src[p] = src[e];
        }
    }
}

// ---------------- cast + dinv scale to fp8: xq = fp8(x * dinv[row]) -------
__global__ void k_cast_q(const float* __restrict__ x, const float* __restrict__ dinv,
                         unsigned int* __restrict__ out, int nw) {
    int i = blockIdx.x * blockDim.x + threadIdx.x;  // word idx; INDIM/4=32 per row
    if (i < nw) {
        float dv = dinv[i >> 5];
        float4 v = ((const float4*)x)[i];
        int w0 = __builtin_amdgcn_cvt_pk_fp8_f32(v.x * dv, v.y * dv, 0, false);
        w0 = __builtin_amdgcn_cvt_pk_fp8_f32(v.z * dv, v.w * dv, w0, true);
        out[i] = (unsigned int)w0;
    }
}

// ---- weight -> fragment-linear bf16 layout ----
template <int K>
__global__ void k_wtf(const float* __restrict__ W, uint4* __restrict__ Wfrag) {
    constexpr int NK = K / 32;
    int c_tile = blockIdx.x / NK;
    int kk = blockIdx.x % NK;
    int lane = threadIdx.x;
    int c = c_tile * 16 + (lane & 15);
    int k0 = kk * 32 + (lane >> 4) * 8;
    unsigned short b[8];
#pragma unroll
    for (int j = 0; j < 8; j++) b[j] = f2bf(W[(size_t)(k0 + j) * HID + c]);
    uint4 o;
    o.x = (unsigned int)b[0] | ((unsigned int)b[1] << 16);
    o.y = (unsigned int)b[2] | ((unsigned int)b[3] << 16);
    o.z = (unsigned int)b[4] | ((unsigned int)b[5] << 16);
    o.w = (unsigned int)b[6] | ((unsigned int)b[7] << 16);
    Wfrag[(size_t)(c_tile * NK + kk) * 64 + lane] = o;
}

// ---- MFMA GEMM, B staged in LDS (fragment-linear, conflict-free) ----
template <int K, int EPI>
__global__ __launch_bounds__(256) void k_gemm_mfma(const unsigned short* __restrict__ Xb,
                                                   const uint4* __restrict__ Wfrag,
                                                   const float* __restrict__ epi,
                                                   void* __restrict__ Yout, int n) {
    constexpr int NK = K / 32;
    __shared__ uint4 bl[4 * NK * 64];

    const int nb = blockIdx.x & 3;          // col quarter
    const int mb = blockIdx.x >> 2;         // row block
    const int r0 = mb * 128;
    const int w = threadIdx.x >> 6;
    const int lane = threadIdx.x & 63;
    const int ar = lane & 15;
    const int ak = (lane >> 4) * 8;

    {
        const uint4* gsrc = Wfrag + (size_t)nb * 4 * NK * 64;
        for (int i = threadIdx.x; i < 4 * NK * 64; i += 256) bl[i] = gsrc[i];
    }

    int arow[2];
#pragma unroll
    for (int rt = 0; rt < 2; rt++) {
        int r = r0 + w * 32 + rt * 16 + ar;
        arow[rt] = (r < n) ? r : n - 1;  // clamp (store guarded)
    }

    f32x4 acc[2][4];
#pragma unroll
    for (int rt = 0; rt < 2; rt++)
#pragma unroll
        for (int ct = 0; ct < 4; ct++) acc[rt][ct] = f32x4{0, 0, 0, 0};

    __syncthreads();

    s16x8 a_cur[2], a_nxt[2];
#pragma unroll
    for (int rt = 0; rt < 2; rt++)
        a_cur[rt] = *(const s16x8*)(Xb + (size_t)arow[rt] * K + ak);

#pragma unroll
    for (int kk = 0; kk < NK; kk++) {
        if (kk + 1 < NK) {
#pragma unroll
            for (int rt = 0; rt < 2; rt++)
                a_nxt[rt] = *(const s16x8*)(Xb + (size_t)arow[rt] * K + (kk + 1) * 32 + ak);
        }
        s16x8 bfrag[4];
#pragma unroll
        for (int ct = 0; ct < 4; ct++)
            bfrag[ct] = ((const s16x8*)bl)[(ct * NK + kk) * 64 + lane];
#pragma unroll
        for (int rt = 0; rt < 2; rt++)
#pragma unroll
            for (int ct = 0; ct < 4; ct++)
                acc[rt][ct] = __builtin_amdgcn_mfma_f32_16x16x32_bf16(a_cur[rt], bfrag[ct],
                                                                      acc[rt][ct], 0, 0, 0);
#pragma unroll
        for (int rt = 0; rt < 2; rt++) a_cur[rt] = a_nxt[rt];
    }

#pragma unroll
    for (int rt = 0; rt < 2; rt++) {
        int rbase = r0 + w * 32 + rt * 16 + (lane >> 4) * 4;
        if constexpr (EPI == 1) {
            unsigned short* Yb = (unsigned short*)Yout;
#pragma unroll
            for (int ct = 0; ct < 4; ct++) {
                int c = nb * 64 + ct * 16 + ar;
                float bc = epi[c];
#pragma unroll
                for (int j = 0; j < 4; j++) {
                    int r = rbase + j;
                    if (r < n) Yb[(size_t)r * HID + c] = f2bf(fmaxf(acc[rt][ct][j] + bc, 0.0f));
                }
            }
        } else {
            unsigned char* Yq = (unsigned char*)Yout;
            float dv[4];
#pragma unroll
            for (int j = 0; j < 4; j++) dv[j] = (rbase + j < n) ? epi[rbase + j] : 0.0f;
#pragma unroll
            for (int ct = 0; ct < 4; ct++) {
                int c = nb * 64 + ct * 16 + ar;
#pragma unroll
                for (int j = 0; j < 4; j++) {
                    int r = rbase + j;
                    if (r < n) {
                        float f = acc[rt][ct][j] * dv[j];
                        int e = __builtin_amdgcn_cvt_pk_fp8_f32(f, f, 0, false);
                        Yq[(size_t)r * HID + c] = (unsigned char)(e & 0xff);
                    }
                }
            }
        }
    }
}

// ---- gather-aggregate fp8 -> bf16, zero-row padded (index n = zeros) ----
template <int D, bool BIASRELU>
__global__ __launch_bounds__(256) void k_agg_q(const unsigned char* __restrict__ Hq,
                                               const float* __restrict__ dinv,
                                               const int* __restrict__ row_start,
                                               const int* __restrict__ csr_src,
                                               const float* __restrict__ bias,
                                               unsigned short* __restrict__ O, int n) {
    constexpr int LPR = D / 16;
    constexpr int EPW = 64 / LPR;
    const int v = blockIdx.x * 4 + (threadIdx.x >> 6);
    const int lane = threadIdx.x & 63;
    const int sub = lane / LPR;
    const int li = lane % LPR;
    if (v >= n) return;
    const uint4* H4 = (const uint4*)Hq;
    f32x2 a[8];
#pragma unroll
    for (int k = 0; k < 8; k++) a[k] = f32x2{0.f, 0.f};
    const int beg = row_start[v], end = row_start[v + 1];
    const int last = end - 1;
    for (int i = beg + sub; i < end; i += 4 * EPW) {
        int j1 = i + EPW, j2 = i + 2 * EPW, j3 = i + 3 * EPW;
        int s0 = csr_src[i];
        int t1 = csr_src[j1 <= last ? j1 : last];
        int t2 = csr_src[j2 <= last ? j2 : last];
        int t3 = csr_src[j3 <= last ? j3 : last];
        int s1 = (j1 < end) ? t1 : n;   // n == zero row
        int s2 = (j2 < end) ? t2 : n;
        int s3 = (j3 < end) ? t3 : n;
        uint4 u0 = H4[(size_t)s0 * LPR + li];
        uint4 u1 = H4[(size_t)s1 * LPR + li];
        uint4 u2 = H4[(size_t)s2 * LPR + li];
        uint4 u3 = H4[(size_t)s3 * LPR + li];
        DEC16P(a, u0); DEC16P(a, u1); DEC16P(a, u2); DEC16P(a, u3);
    }
    // combine partial sums across edge-slots (butterfly)
#pragma unroll
    for (int off = LPR; off < 64; off <<= 1)
#pragma unroll
        for (int k = 0; k < 8; k++) {
            a[k][0] += __shfl_xor(a[k][0], off);
            a[k][1] += __shfl_xor(a[k][1], off);
        }

    if (lane < LPR) {
        uint4 us = H4[(size_t)v * LPR + li];  // self term
        DEC16P(a, us);
        float dv = dinv[v];
        float o[16];
        if constexpr (BIASRELU) {
            const float4* B4 = (const float4*)bias;
#pragma unroll
            for (int q = 0; q < 4; q++) {
                float4 bb = B4[li * 4 + q];
                o[q * 4 + 0] = fmaxf(fmaf(dv, a[q * 2 + 0][0], bb.x), 0.f);
                o[q * 4 + 1] = fmaxf(fmaf(dv, a[q * 2 + 0][1], bb.y), 0.f);
                o[q * 4 + 2] = fmaxf(fmaf(dv, a[q * 2 + 1][0], bb.z), 0.f);
                o[q * 4 + 3] = fmaxf(fmaf(dv, a[q * 2 + 1][1], bb.w), 0.f);
            }
        } else {
#pragma unroll
            for (int k = 0; k < 8; k++) {
                o[k * 2 + 0] = dv * a[k][0];
                o[k * 2 + 1] = dv * a[k][1];
            }
        }
        uint4 ow0, ow1;
        ow0.x = (unsigned int)f2bf(o[0]) | ((unsigned int)f2bf(o[1]) << 16);
        ow0.y = (unsigned int)f2bf(o[2]) | ((unsigned int)f2bf(o[3]) << 16);
        ow0.z = (unsigned int)f2bf(o[4]) | ((unsigned int)f2bf(o[5]) << 16);
        ow0.w = (unsigned int)f2bf(o[6]) | ((unsigned int)f2bf(o[7]) << 16);
        ow1.x = (unsigned int)f2bf(o[8]) | ((unsigned int)f2bf(o[9]) << 16);
        ow1.y = (unsigned int)f2bf(o[10]) | ((unsigned int)f2bf(o[11]) << 16);
        ow1.z = (unsigned int)f2bf(o[12]) | ((unsigned int)f2bf(o[13]) << 16);
        ow1.w = (unsigned int)f2bf(o[14]) | ((unsigned int)f2bf(o[15]) << 16);
        uint4* Op = (uint4*)O + (size_t)v * (2 * LPR) + li * 2;
        Op[0] = ow0;
        Op[1] = ow1;
    }
}

#define BFLO(x) __uint_as_float((x) << 16)
#define BFHI(x) __uint_as_float((x) & 0xffff0000u)
#define ACC8(a, u)                                  \
    do {                                            \
        a[0] += BFLO((u).x); a[1] += BFHI((u).x);   \
        a[2] += BFLO((u).y); a[3] += BFHI((u).y);   \
        a[4] += BFLO((u).z); a[5] += BFHI((u).z);   \
        a[6] += BFLO((u).w); a[7] += BFHI((u).w);   \
    } while (0)

// ---- fused mean-pool + classifier: out[g] = sigmoid(relu(mean@W3+b3)@W4+b4)
__global__ __launch_bounds__(256) void k_poolcls(const unsigned short* __restrict__ Hb,
                                                 const int* __restrict__ batch, int n,
                                                 const float* __restrict__ W3,
                                                 const float* __restrict__ b3,
                                                 const float* __restrict__ W4,
                                                 const float* __restrict__ b4,
                                                 float* __restrict__ out) {
    int g = blockIdx.x;
    int w = threadIdx.x >> 6;
    int lane = threadIdx.x & 63;
    int sub = lane >> 5;
    int li = lane & 31;
    int lo = 0, hi = n;
    while (lo < hi) { int m = (lo + hi) >> 1; if (batch[m] < g) lo = m + 1; else hi = m; }
    int start = lo;
    hi = n;
    while (lo < hi) { int m = (lo + hi) >> 1; if (batch[m] <= g) lo = m + 1; else hi = m; }
    int end = lo;
    const uint4* H4 = (const uint4*)Hb;
    float a[8] = {0, 0, 0, 0, 0, 0, 0, 0};
    for (int v = start + w * 2 + sub; v < end; v += 8) {
        uint4 u = H4[(size_t)v * 32 + li];
        ACC8(a, u);
    }
#pragma unroll
    for (int k = 0; k < 8; k++) a[k] += __shfl_xor(a[k], 32);
    __shared__ float red[4][32][8];
    __shared__ float gr[256];
    if (lane < 32) {
#pragma unroll
        for (int k = 0; k < 8; k++) red[w][li][k] = a[k];
    }
    __syncthreads();
    if (w == 0 && lane < 32) {
        float inv = 1.0f / fmaxf((float)(end - start), 1.0f);
#pragma unroll
        for (int k = 0; k < 8; k++)
            gr[li * 8 + k] = (red[0][li][k] + red[1][li][k] + red[2][li][k] + red[3][li][k]) * inv;
    }
    __syncthreads();
    // classifier on threads 0..127
    __shared__ float red2[2];
    int t = threadIdx.x;
    if (t < 128) {
        float z = b3[t];
        for (int k = 0; k < 256; k++) z += gr[k] * W3[k * 128 + t];
        z = fmaxf(z, 0.0f);
        float p = z * W4[t];
        for (int off = 32; off; off >>= 1) p += __shfl_down(p, off);
        if ((t & 63) == 0) red2[t >> 6] = p;
    }
    __syncthreads();
    if (t == 0) {
        float tot = red2[0] + red2[1] + b4[0];
        out[g] = 1.0f / (1.0f + expf(-tot));
    }
}

// ---------------- launch ----------------
extern "C" void kernel_launch(void* const* d_in, const int* in_sizes, int n_in,
                              void* d_out, int out_size, void* d_ws, size_t ws_size,
                              hipStream_t stream) {
    const float* x  = (const float*)d_in[0];
    const int*   ei = (const int*)d_in[1];
    const int*   batch = (const int*)d_in[2];
    const float* W1 = (const float*)d_in[3];
    const float* b1 = (const float*)d_in[4];
    const float* W2 = (const float*)d_in[5];
    const float* b2 = (const float*)d_in[6];
    const float* W3 = (const float*)d_in[7];
    const float* b3 = (const float*)d_in[8];
    const float* W4 = (const float*)d_in[9];
    const float* b4 = (const float*)d_in[10];

    const int N = in_sizes[2];       // 50000 nodes
    const int E = in_sizes[1] / 2;   // 800000 edges
    const int G = out_size;          // 128 graphs
    const int NB = (N + 255) / 256;

    char* w = (char*)d_ws;
    float* dinv      = (float*)w;  w += ((size_t)N * 4 + 255) & ~(size_t)255;
    int*   cnt       = (int*)w;    w += ((size_t)N * 4 + 255) & ~(size_t)255;
    int*   excl_tmp  = (int*)w;    w += ((size_t)N * 4 + 255) & ~(size_t)255;
    int*   blksum    = (int*)w;    w += 256 * 4;
    int*   row_start = (int*)w;    w += ((size_t)(N + 1) * 4 + 255) & ~(size_t)255;
    int*   cursor    = (int*)w;    w += ((size_t)N * 4 + 255) & ~(size_t)255;
    int*   csr_src   = (int*)w;    w += ((size_t)E * 4 + 255) & ~(size_t)255;
    unsigned char*  xq   = (unsigned char*)w;   w += ((size_t)(N + 1) * INDIM + 255) & ~(size_t)255; // fp8 + zero row
    unsigned char*  Hq   = (unsigned char*)w;   w += ((size_t)(N + 1) * HID + 255) & ~(size_t)255;   // fp8 + zero row
    uint4* wf1 = (uint4*)w;  w += ((size_t)INDIM * HID * 2 + 255) & ~(size_t)255;  // frag-linear bf16
    uint4* wf2 = (uint4*)w;  w += ((size_t)HID * HID * 2 + 255) & ~(size_t)255;    // frag-linear bf16
    unsigned short* bufA = (unsigned short*)w;  w += (size_t)N * INDIM * 2;  // agg1 out (bf16)
    unsigned short* bufB = (unsigned short*)w;  w += (size_t)N * HID * 2;    // h1 / h2 (bf16)

    const int* src = ei;
    const int* dst = ei + E;

    // ---- pad rows + weight layouts ----
    k_zpad<<<1, 64, 0, stream>>>((unsigned int*)(xq + (size_t)N * INDIM),
                                 (unsigned int*)(Hq + (size_t)N * HID));
    k_wtf<INDIM><<<16 * (INDIM / 32), 64, 0, stream>>>(W1, wf1);
    k_wtf<HID><<<16 * (HID / 32), 64, 0, stream>>>(W2, wf2);

    // ---- CSR build + dinv ----
    hipMemsetAsync(cnt, 0, (size_t)N * 4, stream);
    k_count<<<(E / 4 + 255) / 256, 256, 0, stream>>>(dst, E, cnt);
    k_scan_block<<<NB, 256, 0, stream>>>(cnt, excl_tmp, blksum, N);
    k_finalize_rows<<<NB, 256, 0, stream>>>(excl_tmp, blksum, cnt, row_start, cursor, dinv, N, E, NB);
    k_fill<<<NXCD * NSLICE, 256, 0, stream>>>(src, dst, E, cursor, csr_src, N);

    // ---- scaled fp8 cast: xq = fp8(x * dinv[row]) ----
    int nw = N * INDIM / 4;
    k_cast_q<<<(nw + 255) / 256, 256, 0, stream>>>(x, dinv, (unsigned int*)xq, nw);

    const int gemm_blocks = ((N + 127) / 128) * 4;
    const int agg_blocks  = (N + 3) / 4;

    // ---- layer 1: aggregate (fp8 gather) in 128-dim, then GEMM(+bias+relu) ----
    k_agg_q<INDIM, false><<<agg_blocks, 256, 0, stream>>>(xq, dinv, row_start, csr_src, nullptr, bufA, N);
    k_gemm_mfma<INDIM, 1><<<gemm_blocks, 256, 0, stream>>>(bufA, wf1, b1, bufB, N);

    // ---- layer 2: GEMM(*dinv -> fp8), then aggregate(+bias+relu) in 256-dim ----
    k_gemm_mfma<HID, 2><<<gemm_blocks, 256, 0, stream>>>(bufB, wf2, dinv, Hq, N);
    k_agg_q<HID, true><<<agg_blocks, 256, 0, stream>>>(Hq, dinv, row_start, csr_src, b2, bufB, N);

    // ---- fused pool + classifier ----
    k_poolcls<<<G, 256, 0, stream>>>(bufB, batch, N, W3, b3, W4, b4, (float*)d_out);
}